// Round 5
// baseline (635.888 us; speedup 1.0000x reference)
//
#include <hip/hip_runtime.h>

// ChebNet K=3, CSR-by-dst built with 8-way-privatized histograms/cursors to spread
// atomic line contention. All scales factored out of the SpMM:
//   P(z) = -D^{-1/2} A D^{-1/2} z  ==>  G(z')[i] = sum_{e:dst=i} z'[col[e]], scales applied node-wise.

#define BS 256
#define NC 8  // privatization copies

__global__ void k_hist8(const int* __restrict__ src, const int* __restrict__ dst,
                        int* __restrict__ deg8, int* __restrict__ cnt8, int n, int E) {
    int e = blockIdx.x * BS + threadIdx.x;
    int c = blockIdx.x & (NC - 1);
    if (e < E) {
        atomicAdd(&deg8[c * n + src[e]], 1);
        atomicAdd(&cnt8[c * n + dst[e]], 1);
    }
}

// dinv = rsqrt(deg); u = dinv*x; w = -dinv^2
__global__ void k_dinv(const int* __restrict__ deg8, const float* __restrict__ x,
                       float* __restrict__ dinv, float* __restrict__ u,
                       float* __restrict__ w, int n) {
    int i = blockIdx.x * BS + threadIdx.x;
    if (i < n) {
        int d = 0;
        #pragma unroll
        for (int c = 0; c < NC; ++c) d += deg8[c * n + i];
        float df = (float)d;
        float dv = (d > 0) ? rsqrtf(fmaxf(df, 1.0f)) : 0.0f;
        dinv[i] = dv;
        u[i] = dv * x[i];
        w[i] = -dv * dv;
    }
}

// --- exclusive scan over sequence s(t) = cnt8[(t&7)*n + (t>>3)], t in [0, 8n) ---
// scanA: 256 threads x 8 elements = 2048 per block; writes per-element exclusive prefix
// (within block) into cur8 at the same (copy-major) indexing; part[b] = block total.
__global__ void k_scanA(const int* __restrict__ cnt8, int* __restrict__ cur8,
                        int* __restrict__ part, int n) {
    __shared__ int sh[BS];
    int L = NC * n;
    int tid = threadIdx.x;
    int base = blockIdx.x * 2048 + tid * 8;
    int v[8];
    int s = 0;
    #pragma unroll
    for (int k = 0; k < 8; ++k) {
        int t = base + k;
        v[k] = (t < L) ? cnt8[(t & 7) * n + (t >> 3)] : 0;
        s += v[k];
    }
    sh[tid] = s; __syncthreads();
    int acc = s;
    for (int d = 1; d < BS; d <<= 1) {
        int add = (tid >= d) ? sh[tid - d] : 0;
        __syncthreads();
        acc += add; sh[tid] = acc;
        __syncthreads();
    }
    int run = acc - s;  // block-exclusive prefix for this thread's first element
    #pragma unroll
    for (int k = 0; k < 8; ++k) {
        int t = base + k;
        if (t < L) cur8[(t & 7) * n + (t >> 3)] = run;
        run += v[k];
    }
    if (tid == BS - 1) part[blockIdx.x] = acc;
}

__global__ void k_scanB(int* __restrict__ part, int nb) {  // nb <= 512
    __shared__ int sh[512];
    int t = threadIdx.x;
    int v = (t < nb) ? part[t] : 0;
    sh[t] = v; __syncthreads();
    int acc = v;
    for (int d = 1; d < 512; d <<= 1) {
        int add = (t >= d) ? sh[t - d] : 0;
        __syncthreads();
        acc += add; sh[t] = acc;
        __syncthreads();
    }
    if (t < nb) part[t] = acc - v;  // exclusive
}

// add block offsets; emit rowptr (row start = prefix at copy 0)
__global__ void k_scanC(int* __restrict__ cur8, const int* __restrict__ part,
                        int* __restrict__ rowptr, int n, int E) {
    int L = NC * n;
    int t = blockIdx.x * BS + threadIdx.x;
    if (t < L) {
        int idx = (t & 7) * n + (t >> 3);
        int val = cur8[idx] + part[t >> 11];
        cur8[idx] = val;
        if ((t & 7) == 0) rowptr[t >> 3] = val;
    }
    if (t == 0) rowptr[n] = E;
}

// counting-sort fill; copy assignment MUST match k_hist8 (same grid geometry).
__global__ void k_build(const int* __restrict__ src, const int* __restrict__ dst,
                        int* __restrict__ cur8, int* __restrict__ colv, int n, int E) {
    int e = blockIdx.x * BS + threadIdx.x;
    int c = blockIdx.x & (NC - 1);
    if (e < E) {
        int pos = atomicAdd(&cur8[c * n + dst[e]], 1);
        colv[pos] = src[e];
    }
}

// scalar gather-sum: g[i] = sum val over row; optionally also vout[i] = w[i]*g[i]
__global__ void k_prop_s(const int* __restrict__ rowptr, const int* __restrict__ colv,
                         const float* __restrict__ in, float* __restrict__ g,
                         float* __restrict__ vout, const float* __restrict__ w, int n) {
    int i = blockIdx.x * BS + threadIdx.x;
    if (i < n) {
        int b = rowptr[i], e = rowptr[i + 1];
        float s = 0.0f;
        for (int j = b; j < e; ++j) s += in[colv[j]];
        g[i] = s;
        if (vout) vout[i] = w[i] * s;
    }
}

// 32-dim gather-sum: 8 lanes/node, float4/lane. Optional per-source scale sc[s].
__global__ void k_prop_v(const int* __restrict__ rowptr, const int* __restrict__ colv,
                         const float* __restrict__ in, float* __restrict__ out,
                         const float* __restrict__ sc, int n) {
    int t = blockIdx.x * BS + threadIdx.x;
    int node = t >> 3;
    if (node < n) {
        int ln4 = (t & 7) << 2;
        int b = rowptr[node], e = rowptr[node + 1];
        float4 acc = make_float4(0.f, 0.f, 0.f, 0.f);
        for (int j = b; j < e; ++j) {
            int s = colv[j];
            float m = sc ? sc[s] : 1.0f;
            float4 v = *reinterpret_cast<const float4*>(in + s * 32 + ln4);
            acc.x += m * v.x; acc.y += m * v.y; acc.z += m * v.z; acc.w += m * v.w;
        }
        *reinterpret_cast<float4*>(out + node * 32 + ln4) = acc;
    }
}

// layer1: Tx1 = -dinv*g1; Tx2 = -2*dinv*g2 - x; h = relu(x*W1[0]+Tx1*W1[1]+Tx2*W1[2]+b1)
// also hs = dinv*h (input to next gather)
__global__ void k_layer1(const float* __restrict__ x, const float* __restrict__ g1,
                         const float* __restrict__ g2, const float* __restrict__ dinv,
                         const float* __restrict__ W1, const float* __restrict__ b1,
                         float* __restrict__ h, float* __restrict__ hs, int n) {
    int idx = blockIdx.x * BS + threadIdx.x;
    if (idx < n * 32) {
        int i = idx >> 5, f = idx & 31;
        float x0 = x[i], dv = dinv[i];
        float t1 = -dv * g1[i];
        float t2 = -2.0f * dv * g2[i] - x0;
        float v = x0 * W1[f] + t1 * W1[32 + f] + t2 * W1[64 + f] + b1[f];
        v = fmaxf(v, 0.0f);
        h[idx] = v;
        hs[idx] = dv * v;
    }
}

// layer2+fc: s1 = -dinv*gA; s2 = -2*dinv*gB - h; h2 = relu(h@W2[0]+s1@W2[1]+s2@W2[2]+b2)
// out = h2 @ Wfc + bfc.  Block = 8 nodes x 32 features; W2 in LDS.
__global__ void k_layer2_fc(const float* __restrict__ h, const float* __restrict__ gA,
                            const float* __restrict__ gB, const float* __restrict__ dinv,
                            const float* __restrict__ W2, const float* __restrict__ b2,
                            const float* __restrict__ Wfc, const float* __restrict__ bfc,
                            float* __restrict__ out, int n) {
    __shared__ float W2s[3 * 32 * 32];
    int tid = threadIdx.x;
    for (int j = tid; j < 3 * 32 * 32; j += BS) W2s[j] = W2[j];
    __syncthreads();
    int f = tid & 31;
    int i = blockIdx.x * 8 + (tid >> 5);
    float acc = 0.0f;
    if (i < n) {
        float dv = dinv[i];
        acc = b2[f];
        const float* hr = h  + (size_t)i * 32;
        const float* ga = gA + (size_t)i * 32;
        const float* gb = gB + (size_t)i * 32;
        #pragma unroll
        for (int k = 0; k < 32; ++k) {
            float hk  = hr[k];
            float s1k = -dv * ga[k];
            float s2k = -2.0f * dv * gb[k] - hk;
            acc += hk * W2s[k * 32 + f] + s1k * W2s[1024 + k * 32 + f] + s2k * W2s[2048 + k * 32 + f];
        }
        acc = fmaxf(acc, 0.0f) * Wfc[f];
    }
    #pragma unroll
    for (int m = 16; m >= 1; m >>= 1) acc += __shfl_xor(acc, m, 32);
    if (i < n && f == 0) out[i] = acc + bfc[0];
}

extern "C" void kernel_launch(void* const* d_in, const int* in_sizes, int n_in,
                              void* d_out, int out_size, void* d_ws, size_t ws_size,
                              hipStream_t stream) {
    const float* x   = (const float*)d_in[0];
    const int*   ei  = (const int*)d_in[1];
    const float* W1  = (const float*)d_in[2];
    const float* b1  = (const float*)d_in[3];
    const float* W2  = (const float*)d_in[4];
    const float* b2  = (const float*)d_in[5];
    const float* Wfc = (const float*)d_in[6];
    const float* bfc = (const float*)d_in[7];
    float* out = (float*)d_out;

    const int n = in_sizes[0];
    const int E = in_sizes[1] / 2;
    const int* src = ei;
    const int* dst = ei + E;

    // workspace layout (4B words), ~55 MB total
    int*   cnt8   = (int*)d_ws;                  // 8n (zeroed)
    int*   deg8   = cnt8 + (size_t)NC * n;       // 8n (zeroed); becomes cur8 after k_dinv
    int*   cur8   = deg8;                        // alias: scan writes cursors here
    int*   rowptr = deg8 + (size_t)NC * n;       // n+8
    int*   part   = rowptr + n + 8;              // 512
    float* dinv   = (float*)(part + 512);        // n
    float* u      = dinv + n;                    // n
    float* w      = u + n;                       // n
    float* g1     = w + n;                       // n
    float* v1     = g1 + n;                      // n
    float* g2     = v1 + n;                      // n
    int*   colv   = (int*)(g2 + n);              // E
    float* h      = (float*)(colv + E);          // 32n
    float* hs     = h + (size_t)32 * n;          // 32n; becomes gB after prop_v1 consumes it
    float* gA     = hs + (size_t)32 * n;         // 32n
    float* gB     = hs;                          // alias

    hipMemsetAsync(d_ws, 0, (size_t)2 * NC * n * sizeof(int), stream);

    const int EB = (E + BS - 1) / BS;
    const int NB = (n + BS - 1) / BS;
    const int L  = NC * n;
    const int NBA = (L + 2047) / 2048;           // scanA blocks (<=512)

    k_hist8<<<EB, BS, 0, stream>>>(src, dst, deg8, cnt8, n, E);
    k_dinv <<<NB, BS, 0, stream>>>(deg8, x, dinv, u, w, n);
    k_scanA<<<NBA, BS, 0, stream>>>(cnt8, cur8, part, n);
    k_scanB<<<1, 512, 0, stream>>>(part, NBA);
    k_scanC<<<(L + BS - 1) / BS, BS, 0, stream>>>(cur8, part, rowptr, n, E);
    k_build<<<EB, BS, 0, stream>>>(src, dst, cur8, colv, n, E);

    // layer 1 (scalar)
    k_prop_s<<<NB, BS, 0, stream>>>(rowptr, colv, u, g1, v1, w, n);
    k_prop_s<<<NB, BS, 0, stream>>>(rowptr, colv, v1, g2, nullptr, nullptr, n);
    k_layer1<<<(n * 32 + BS - 1) / BS, BS, 0, stream>>>(x, g1, g2, dinv, W1, b1, h, hs, n);

    // layer 2 (32-dim)
    k_prop_v<<<(n * 8 + BS - 1) / BS, BS, 0, stream>>>(rowptr, colv, hs, gA, nullptr, n);
    k_prop_v<<<(n * 8 + BS - 1) / BS, BS, 0, stream>>>(rowptr, colv, gA, gB, w, n);
    k_layer2_fc<<<(n + 7) / 8, BS, 0, stream>>>(h, gA, gB, dinv, W2, b2, Wfc, bfc, out, n);
}

// Round 7
// 559.190 us; speedup vs baseline: 1.1372x; 1.1372x over previous
//
#include <hip/hip_runtime.h>

// ChebNet K=3. CSR-by-dst built via XCD-partitioned arenas (copy c = blockIdx&7 owns
// a disjoint arena region, so scattered build writes stay in one XCD's L2 -> no
// cross-XCD dirty-line ping-pong), then merged into packed colv. Gather-side props
// with 4-deep load pipelining. All norm scales factored into node-wise ops.

#define BS 256
#define NC 8  // privatization copies (~XCDs)

__global__ void k_hist8(const int* __restrict__ src, const int* __restrict__ dst,
                        int* __restrict__ deg8, int* __restrict__ cnt8, int n, int E) {
    int e = blockIdx.x * BS + threadIdx.x;
    int c = blockIdx.x & (NC - 1);
    if (e < E) {
        atomicAdd(&deg8[c * n + src[e]], 1);
        atomicAdd(&cnt8[c * n + dst[e]], 1);
    }
}

// dinv = rsqrt(deg); u = dinv*x; w = -dinv^2; cnt[i] = sum_c cnt8[c][i]
__global__ void k_dinv2(const int* __restrict__ deg8, const int* __restrict__ cnt8,
                        const float* __restrict__ x, float* __restrict__ dinv,
                        float* __restrict__ u, float* __restrict__ w,
                        int* __restrict__ cnt, int n) {
    int i = blockIdx.x * BS + threadIdx.x;
    if (i < n) {
        int d = 0, ci = 0;
        #pragma unroll
        for (int c = 0; c < NC; ++c) { d += deg8[c * n + i]; ci += cnt8[c * n + i]; }
        float df = (float)d;
        float dv = (d > 0) ? rsqrtf(fmaxf(df, 1.0f)) : 0.0f;
        dinv[i] = dv;
        u[i] = dv * x[i];
        w[i] = -dv * dv;
        cnt[i] = ci;
    }
}

// --- scan 1: exclusive scan of the FLAT cnt8 array (copy-major) -> cur8 = arena offsets ---
__global__ void k_scanA_lin(const int* __restrict__ in, int* __restrict__ outp,
                            int* __restrict__ part, int L) {
    __shared__ int sh[BS];
    int tid = threadIdx.x;
    int base = blockIdx.x * 2048 + tid * 8;
    int v[8];
    int s = 0;
    #pragma unroll
    for (int k = 0; k < 8; ++k) {
        int t = base + k;
        v[k] = (t < L) ? in[t] : 0;
        s += v[k];
    }
    sh[tid] = s; __syncthreads();
    int acc = s;
    for (int d = 1; d < BS; d <<= 1) {
        int add = (tid >= d) ? sh[tid - d] : 0;
        __syncthreads();
        acc += add; sh[tid] = acc;
        __syncthreads();
    }
    int run = acc - s;
    #pragma unroll
    for (int k = 0; k < 8; ++k) {
        int t = base + k;
        if (t < L) outp[t] = run;
        run += v[k];
    }
    if (tid == BS - 1) part[blockIdx.x] = acc;
}

__global__ void k_scanB(int* __restrict__ part, int nb) {  // nb <= 512
    __shared__ int sh[512];
    int t = threadIdx.x;
    int v = (t < nb) ? part[t] : 0;
    sh[t] = v; __syncthreads();
    int acc = v;
    for (int d = 1; d < 512; d <<= 1) {
        int add = (t >= d) ? sh[t - d] : 0;
        __syncthreads();
        acc += add; sh[t] = acc;
        __syncthreads();
    }
    if (t < nb) part[t] = acc - v;  // exclusive
}

__global__ void k_scanC_lin(int* __restrict__ outp, const int* __restrict__ part, int L) {
    int t = blockIdx.x * BS + threadIdx.x;
    if (t < L) outp[t] += part[t >> 11];
}

// --- scan 2: exclusive scan of node totals cnt -> rowptr (packed colv row starts) ---
__global__ void k_scan2A(const int* __restrict__ cnt, int* __restrict__ rowptr,
                         int* __restrict__ part, int n) {
    __shared__ int sh[BS];
    int t = threadIdx.x, i = blockIdx.x * BS + t;
    int v = (i < n) ? cnt[i] : 0;
    sh[t] = v; __syncthreads();
    int acc = v;
    for (int d = 1; d < BS; d <<= 1) {
        int add = (t >= d) ? sh[t - d] : 0;
        __syncthreads();
        acc += add; sh[t] = acc;
        __syncthreads();
    }
    if (i < n) rowptr[i] = acc - v;
    if (t == BS - 1) part[blockIdx.x] = acc;
}

__global__ void k_scan2C(int* __restrict__ rowptr, const int* __restrict__ part, int n, int E) {
    int i = blockIdx.x * BS + threadIdx.x;
    if (i < n) rowptr[i] += part[i >> 8];
    if (i == n) rowptr[n] = E;
}

// arena fill: copy c's region written only by blocks ==c (mod NC)  (same geometry as k_hist8)
__global__ void k_build2(const int* __restrict__ src, const int* __restrict__ dst,
                         int* __restrict__ cur8, int* __restrict__ arena, int n, int E) {
    int e = blockIdx.x * BS + threadIdx.x;
    int c = blockIdx.x & (NC - 1);
    if (e < E) {
        int pos = atomicAdd(&cur8[c * n + dst[e]], 1);
        arena[pos] = src[e];
    }
}

// merge 8 per-copy fragments of each row into packed colv. 8 lanes per node.
// After k_build2, cur8[c*n+i] = fragment END; start = end - cnt8[c*n+i].
__global__ void k_merge(const int* __restrict__ arena, const int* __restrict__ cur8,
                        const int* __restrict__ cnt8, const int* __restrict__ rowptr,
                        int* __restrict__ colv, int n) {
    int t = blockIdx.x * BS + threadIdx.x;
    int i = t >> 3, c = t & 7;
    if (i >= n) return;
    int len = cnt8[c * n + i];
    int end = cur8[c * n + i];
    int pre = len;
    #pragma unroll
    for (int d = 1; d < 8; d <<= 1) {
        int o = __shfl_up(pre, d, 8);
        if ((threadIdx.x & 7) >= d) pre += o;
    }
    pre -= len;  // exclusive prefix of lengths within the 8-lane group
    int p = rowptr[i] + pre;
    for (int j = end - len; j < end; ++j) colv[p++] = arena[j];
}

// scalar gather-sum with 4-deep load pipelining
__global__ void k_prop_s(const int* __restrict__ rowptr, const int* __restrict__ colv,
                         const float* __restrict__ in, float* __restrict__ g,
                         float* __restrict__ vout, const float* __restrict__ w, int n) {
    int i = blockIdx.x * BS + threadIdx.x;
    if (i >= n) return;
    int b = rowptr[i], e = rowptr[i + 1];
    float s = 0.0f;
    int j = b;
    for (; j + 4 <= e; j += 4) {
        int s0 = colv[j], s1 = colv[j + 1], s2 = colv[j + 2], s3 = colv[j + 3];
        float a0 = in[s0], a1 = in[s1], a2 = in[s2], a3 = in[s3];
        s += (a0 + a1) + (a2 + a3);
    }
    for (; j < e; ++j) s += in[colv[j]];
    g[i] = s;
    if (vout) vout[i] = w[i] * s;
}

// 32-dim gather-sum: 8 lanes/node, float4/lane, 4 gathers in flight.
__global__ void k_prop_v(const int* __restrict__ rowptr, const int* __restrict__ colv,
                         const float* __restrict__ in, float* __restrict__ out,
                         const float* __restrict__ sc, int n) {
    int t = blockIdx.x * BS + threadIdx.x;
    int node = t >> 3;
    if (node >= n) return;
    int ln4 = (t & 7) << 2;
    int b = rowptr[node], e = rowptr[node + 1];
    float4 acc = make_float4(0.f, 0.f, 0.f, 0.f);
    int j = b;
    for (; j + 4 <= e; j += 4) {
        int s0 = colv[j], s1 = colv[j + 1], s2 = colv[j + 2], s3 = colv[j + 3];
        float4 v0 = *reinterpret_cast<const float4*>(in + s0 * 32 + ln4);
        float4 v1 = *reinterpret_cast<const float4*>(in + s1 * 32 + ln4);
        float4 v2 = *reinterpret_cast<const float4*>(in + s2 * 32 + ln4);
        float4 v3 = *reinterpret_cast<const float4*>(in + s3 * 32 + ln4);
        float m0 = 1.f, m1 = 1.f, m2 = 1.f, m3 = 1.f;
        if (sc) { m0 = sc[s0]; m1 = sc[s1]; m2 = sc[s2]; m3 = sc[s3]; }
        acc.x += m0 * v0.x + m1 * v1.x + m2 * v2.x + m3 * v3.x;
        acc.y += m0 * v0.y + m1 * v1.y + m2 * v2.y + m3 * v3.y;
        acc.z += m0 * v0.z + m1 * v1.z + m2 * v2.z + m3 * v3.z;
        acc.w += m0 * v0.w + m1 * v1.w + m2 * v2.w + m3 * v3.w;
    }
    for (; j < e; ++j) {
        int s = colv[j];
        float m = sc ? sc[s] : 1.0f;
        float4 v = *reinterpret_cast<const float4*>(in + s * 32 + ln4);
        acc.x += m * v.x; acc.y += m * v.y; acc.z += m * v.z; acc.w += m * v.w;
    }
    *reinterpret_cast<float4*>(out + node * 32 + ln4) = acc;
}

// layer1: Tx1 = -dinv*g1; Tx2 = -2*dinv*g2 - x; h = relu(x*W1[0]+Tx1*W1[1]+Tx2*W1[2]+b1); hs = dinv*h
__global__ void k_layer1(const float* __restrict__ x, const float* __restrict__ g1,
                         const float* __restrict__ g2, const float* __restrict__ dinv,
                         const float* __restrict__ W1, const float* __restrict__ b1,
                         float* __restrict__ h, float* __restrict__ hs, int n) {
    int idx = blockIdx.x * BS + threadIdx.x;
    if (idx < n * 32) {
        int i = idx >> 5, f = idx & 31;
        float x0 = x[i], dv = dinv[i];
        float t1 = -dv * g1[i];
        float t2 = -2.0f * dv * g2[i] - x0;
        float v = x0 * W1[f] + t1 * W1[32 + f] + t2 * W1[64 + f] + b1[f];
        v = fmaxf(v, 0.0f);
        h[idx] = v;
        hs[idx] = dv * v;
    }
}

// layer2+fc: s1 = -dinv*gA; s2 = -2*dinv*gB - h; h2 = relu(h@W2[0]+s1@W2[1]+s2@W2[2]+b2); out = h2@Wfc+bfc
__global__ void k_layer2_fc(const float* __restrict__ h, const float* __restrict__ gA,
                            const float* __restrict__ gB, const float* __restrict__ dinv,
                            const float* __restrict__ W2, const float* __restrict__ b2,
                            const float* __restrict__ Wfc, const float* __restrict__ bfc,
                            float* __restrict__ out, int n) {
    __shared__ float W2s[3 * 32 * 32];
    int tid = threadIdx.x;
    for (int j = tid; j < 3 * 32 * 32; j += BS) W2s[j] = W2[j];
    __syncthreads();
    int f = tid & 31;
    int i = blockIdx.x * 8 + (tid >> 5);
    float acc = 0.0f;
    if (i < n) {
        float dv = dinv[i];
        acc = b2[f];
        const float* hr = h  + (size_t)i * 32;
        const float* ga = gA + (size_t)i * 32;
        const float* gb = gB + (size_t)i * 32;
        #pragma unroll
        for (int k = 0; k < 32; ++k) {
            float hk  = hr[k];
            float s1k = -dv * ga[k];
            float s2k = -2.0f * dv * gb[k] - hk;
            acc += hk * W2s[k * 32 + f] + s1k * W2s[1024 + k * 32 + f] + s2k * W2s[2048 + k * 32 + f];
        }
        acc = fmaxf(acc, 0.0f) * Wfc[f];
    }
    #pragma unroll
    for (int m = 16; m >= 1; m >>= 1) acc += __shfl_xor(acc, m, 32);
    if (i < n && f == 0) out[i] = acc + bfc[0];
}

extern "C" void kernel_launch(void* const* d_in, const int* in_sizes, int n_in,
                              void* d_out, int out_size, void* d_ws, size_t ws_size,
                              hipStream_t stream) {
    const float* x   = (const float*)d_in[0];
    const int*   ei  = (const int*)d_in[1];
    const float* W1  = (const float*)d_in[2];
    const float* b1  = (const float*)d_in[3];
    const float* W2  = (const float*)d_in[4];
    const float* b2  = (const float*)d_in[5];
    const float* Wfc = (const float*)d_in[6];
    const float* bfc = (const float*)d_in[7];
    float* out = (float*)d_out;

    const int n = in_sizes[0];
    const int E = in_sizes[1] / 2;
    const int* src = ei;
    const int* dst = ei + E;

    // workspace layout (4B words)
    int*   cnt8   = (int*)d_ws;                  // 8n (zeroed)
    int*   deg8   = cnt8 + (size_t)NC * n;       // 8n (zeroed); reused as cur8 after k_dinv2
    int*   cur8   = deg8;                        // alias
    int*   cnt    = deg8 + (size_t)NC * n;       // n
    int*   rowptr = cnt + n;                     // n+4
    int*   part   = rowptr + n + 4;              // 512
    float* dinv   = (float*)(part + 512);        // n
    float* u      = dinv + n;                    // n
    float* w      = u + n;                       // n
    float* g1     = w + n;                       // n
    float* v1     = g1 + n;                      // n
    float* g2     = v1 + n;                      // n
    int*   colv   = (int*)(g2 + n);              // E
    float* h      = (float*)(colv + E);          // 32n
    float* hs     = h + (size_t)32 * n;          // 32n; reused as gB
    float* gA     = hs + (size_t)32 * n;         // 32n
    float* gB     = hs;                          // alias
    int*   arena  = (int*)h;                     // E ints, overlaps h (dead until k_layer1)

    hipMemsetAsync(d_ws, 0, (size_t)2 * NC * n * sizeof(int), stream);

    const int EB  = (E + BS - 1) / BS;
    const int NB  = (n + BS - 1) / BS;
    const int L   = NC * n;
    const int NBA = (L + 2047) / 2048;           // <=512

    k_hist8<<<EB, BS, 0, stream>>>(src, dst, deg8, cnt8, n, E);
    k_dinv2<<<NB, BS, 0, stream>>>(deg8, cnt8, x, dinv, u, w, cnt, n);
    // scan 1: flat cnt8 -> cur8 (arena offsets, copy-major so each copy region is disjoint)
    k_scanA_lin<<<NBA, BS, 0, stream>>>(cnt8, cur8, part, L);
    k_scanB<<<1, 512, 0, stream>>>(part, NBA);
    k_scanC_lin<<<(L + BS - 1) / BS, BS, 0, stream>>>(cur8, part, L);
    // scan 2: cnt -> rowptr (packed row starts)
    k_scan2A<<<NB, BS, 0, stream>>>(cnt, rowptr, part, n);
    k_scanB<<<1, 512, 0, stream>>>(part, NB);
    k_scan2C<<<NB + 1, BS, 0, stream>>>(rowptr, part, n, E);
    // arena fill + merge to packed colv
    k_build2<<<EB, BS, 0, stream>>>(src, dst, cur8, arena, n, E);
    k_merge<<<(n * 8 + BS - 1) / BS, BS, 0, stream>>>(arena, cur8, cnt8, rowptr, colv, n);

    // layer 1 (scalar)
    k_prop_s<<<NB, BS, 0, stream>>>(rowptr, colv, u, g1, v1, w, n);
    k_prop_s<<<NB, BS, 0, stream>>>(rowptr, colv, v1, g2, nullptr, nullptr, n);
    k_layer1<<<(n * 32 + BS - 1) / BS, BS, 0, stream>>>(x, g1, g2, dinv, W1, b1, h, hs, n);

    // layer 2 (32-dim)
    k_prop_v<<<(n * 8 + BS - 1) / BS, BS, 0, stream>>>(rowptr, colv, hs, gA, nullptr, n);
    k_prop_v<<<(n * 8 + BS - 1) / BS, BS, 0, stream>>>(rowptr, colv, gA, gB, w, n);
    k_layer2_fc<<<(n + 7) / 8, BS, 0, stream>>>(h, gA, gB, dinv, W2, b2, Wfc, bfc, out, n);
}

// Round 8
// 467.191 us; speedup vs baseline: 1.3611x; 1.1969x over previous
//
#include <hip/hip_runtime.h>

// ChebNet K=3. CSR-by-dst. Histograms via LDS-range aggregation (no scattered global
// atomics: each block owns a 25K-counter LDS range, flushes coalesced+zero-skipped).
// Build via XCD-partitioned arenas (copy c = blockIdx&7), merged to packed colv.
// Gather-side props with 8-deep load pipelining. Norm scales factored node-wise.

#define BS 256
#define NC 8      // arena copies (~XCDs); copy of edge e = (e>>8) & 7 == buildBlockIdx & 7
#define NR 4      // histogram node ranges
#define HB 1024   // histogram block size
#define RCAP 25600

// dst-count histogram, per-copy (copy must match k_build2: c = piece index & 7, piece = e>>8).
// grid = NR*NC*8 blocks: b = r*64 + c*8 + j; block reads pieces p = c+8j+64k (k in steps of 4 subs).
__global__ __launch_bounds__(HB, 1) void k_hist_cnt(const int* __restrict__ dst,
                                                    int* __restrict__ cnt8, int n, int E) {
    __shared__ int lds[RCAP];
    const int R = (n + NR - 1) / NR;
    int b = blockIdx.x;
    int r = b >> 6, c = (b >> 3) & 7, j = b & 7;
    int t = threadIdx.x;
    for (int q = t; q < RCAP; q += HB) lds[q] = 0;
    __syncthreads();
    int lo = r * R, hi = min(lo + R, n);
    int P = (E + 255) >> 8;
    int sub = t >> 8, lane = t & 255;
    for (int m = 0;; ++m) {
        int p = c + 8 * j + 64 * (4 * m + sub);
        if (p >= P) break;
        int e = (p << 8) + lane;
        if (e < E) {
            int d = dst[e];
            if (d >= lo && d < hi) atomicAdd(&lds[d - lo], 1);
        }
    }
    __syncthreads();
    int base = c * n + lo, len = hi - lo;
    for (int q = t; q < len; q += HB) {
        int v = lds[q];
        if (v) atomicAdd(&cnt8[base + q], v);
    }
}

// src-degree histogram (single output array). grid = NR*64 blocks: b = r*64 + j.
__global__ __launch_bounds__(HB, 1) void k_hist_deg(const int* __restrict__ src,
                                                    int* __restrict__ deg, int n, int E) {
    __shared__ int lds[RCAP];
    const int R = (n + NR - 1) / NR;
    int b = blockIdx.x;
    int r = b >> 6, j = b & 63;
    int t = threadIdx.x;
    for (int q = t; q < RCAP; q += HB) lds[q] = 0;
    __syncthreads();
    int lo = r * R, hi = min(lo + R, n);
    int CE = (E + 63) >> 6;
    int e0 = j * CE, e1 = min(e0 + CE, E);
    for (int e = e0 + t; e < e1; e += HB) {
        int s = src[e];
        if (s >= lo && s < hi) atomicAdd(&lds[s - lo], 1);
    }
    __syncthreads();
    int len = hi - lo;
    for (int q = t; q < len; q += HB) {
        int v = lds[q];
        if (v) atomicAdd(&deg[lo + q], v);
    }
}

// dinv = rsqrt(deg); u = dinv*x; w = -dinv^2; cnt[i] = sum_c cnt8[c][i]
__global__ void k_dinv2(const int* __restrict__ deg, const int* __restrict__ cnt8,
                        const float* __restrict__ x, float* __restrict__ dinv,
                        float* __restrict__ u, float* __restrict__ w,
                        int* __restrict__ cnt, int n) {
    int i = blockIdx.x * BS + threadIdx.x;
    if (i < n) {
        int d = deg[i], ci = 0;
        #pragma unroll
        for (int c = 0; c < NC; ++c) ci += cnt8[c * n + i];
        float df = (float)d;
        float dv = (d > 0) ? rsqrtf(fmaxf(df, 1.0f)) : 0.0f;
        dinv[i] = dv;
        u[i] = dv * x[i];
        w[i] = -dv * dv;
        cnt[i] = ci;
    }
}

// --- scan 1: exclusive scan of flat cnt8 (copy-major) -> cur8 = arena offsets ---
__global__ void k_scanA_lin(const int* __restrict__ in, int* __restrict__ outp,
                            int* __restrict__ part, int L) {
    __shared__ int sh[BS];
    int tid = threadIdx.x;
    int base = blockIdx.x * 2048 + tid * 8;
    int v[8];
    int s = 0;
    #pragma unroll
    for (int k = 0; k < 8; ++k) {
        int t = base + k;
        v[k] = (t < L) ? in[t] : 0;
        s += v[k];
    }
    sh[tid] = s; __syncthreads();
    int acc = s;
    for (int d = 1; d < BS; d <<= 1) {
        int add = (tid >= d) ? sh[tid - d] : 0;
        __syncthreads();
        acc += add; sh[tid] = acc;
        __syncthreads();
    }
    int run = acc - s;
    #pragma unroll
    for (int k = 0; k < 8; ++k) {
        int t = base + k;
        if (t < L) outp[t] = run;
        run += v[k];
    }
    if (tid == BS - 1) part[blockIdx.x] = acc;
}

__global__ void k_scanB(int* __restrict__ part, int nb) {  // nb <= 512
    __shared__ int sh[512];
    int t = threadIdx.x;
    int v = (t < nb) ? part[t] : 0;
    sh[t] = v; __syncthreads();
    int acc = v;
    for (int d = 1; d < 512; d <<= 1) {
        int add = (t >= d) ? sh[t - d] : 0;
        __syncthreads();
        acc += add; sh[t] = acc;
        __syncthreads();
    }
    if (t < nb) part[t] = acc - v;  // exclusive
}

__global__ void k_scanC_lin(int* __restrict__ outp, const int* __restrict__ part, int L) {
    int t = blockIdx.x * BS + threadIdx.x;
    if (t < L) outp[t] += part[t >> 11];
}

// --- scan 2: exclusive scan of node totals cnt -> rowptr ---
__global__ void k_scan2A(const int* __restrict__ cnt, int* __restrict__ rowptr,
                         int* __restrict__ part, int n) {
    __shared__ int sh[BS];
    int t = threadIdx.x, i = blockIdx.x * BS + t;
    int v = (i < n) ? cnt[i] : 0;
    sh[t] = v; __syncthreads();
    int acc = v;
    for (int d = 1; d < BS; d <<= 1) {
        int add = (t >= d) ? sh[t - d] : 0;
        __syncthreads();
        acc += add; sh[t] = acc;
        __syncthreads();
    }
    if (i < n) rowptr[i] = acc - v;
    if (t == BS - 1) part[blockIdx.x] = acc;
}

__global__ void k_scan2C(int* __restrict__ rowptr, const int* __restrict__ part, int n, int E) {
    int i = blockIdx.x * BS + threadIdx.x;
    if (i < n) rowptr[i] += part[i >> 8];
    if (i == n) rowptr[n] = E;
}

// arena fill: copy c = blockIdx&7 (matches k_hist_cnt's piece&7 assignment)
__global__ void k_build2(const int* __restrict__ src, const int* __restrict__ dst,
                         int* __restrict__ cur8, int* __restrict__ arena, int n, int E) {
    int e = blockIdx.x * BS + threadIdx.x;
    int c = blockIdx.x & (NC - 1);
    if (e < E) {
        int pos = atomicAdd(&cur8[c * n + dst[e]], 1);
        arena[pos] = src[e];
    }
}

// merge 8 per-copy fragments of each row into packed colv. 8 lanes per node.
__global__ void k_merge(const int* __restrict__ arena, const int* __restrict__ cur8,
                        const int* __restrict__ cnt8, const int* __restrict__ rowptr,
                        int* __restrict__ colv, int n) {
    int t = blockIdx.x * BS + threadIdx.x;
    int i = t >> 3, c = t & 7;
    if (i >= n) return;
    int len = cnt8[c * n + i];
    int end = cur8[c * n + i];
    int pre = len;
    #pragma unroll
    for (int d = 1; d < 8; d <<= 1) {
        int o = __shfl_up(pre, d, 8);
        if ((threadIdx.x & 7) >= d) pre += o;
    }
    pre -= len;
    int p = rowptr[i] + pre;
    for (int j = end - len; j < end; ++j) colv[p++] = arena[j];
}

// scalar gather-sum with 4-deep load pipelining
__global__ void k_prop_s(const int* __restrict__ rowptr, const int* __restrict__ colv,
                         const float* __restrict__ in, float* __restrict__ g,
                         float* __restrict__ vout, const float* __restrict__ w, int n) {
    int i = blockIdx.x * BS + threadIdx.x;
    if (i >= n) return;
    int b = rowptr[i], e = rowptr[i + 1];
    float s = 0.0f;
    int j = b;
    for (; j + 4 <= e; j += 4) {
        int s0 = colv[j], s1 = colv[j + 1], s2 = colv[j + 2], s3 = colv[j + 3];
        float a0 = in[s0], a1 = in[s1], a2 = in[s2], a3 = in[s3];
        s += (a0 + a1) + (a2 + a3);
    }
    for (; j < e; ++j) s += in[colv[j]];
    g[i] = s;
    if (vout) vout[i] = w[i] * s;
}

// 32-dim gather-sum: 8 lanes/node, float4/lane, 8 gathers in flight.
__global__ void k_prop_v(const int* __restrict__ rowptr, const int* __restrict__ colv,
                         const float* __restrict__ in, float* __restrict__ out,
                         const float* __restrict__ sc, int n) {
    int t = blockIdx.x * BS + threadIdx.x;
    int node = t >> 3;
    if (node >= n) return;
    int ln4 = (t & 7) << 2;
    int b = rowptr[node], e = rowptr[node + 1];
    float4 acc = make_float4(0.f, 0.f, 0.f, 0.f);
    int j = b;
    for (; j + 8 <= e; j += 8) {
        int sx[8];
        #pragma unroll
        for (int q = 0; q < 8; ++q) sx[q] = colv[j + q];
        float4 vv[8];
        #pragma unroll
        for (int q = 0; q < 8; ++q) vv[q] = *reinterpret_cast<const float4*>(in + sx[q] * 32 + ln4);
        float mm[8];
        #pragma unroll
        for (int q = 0; q < 8; ++q) mm[q] = sc ? sc[sx[q]] : 1.0f;
        #pragma unroll
        for (int q = 0; q < 8; ++q) {
            acc.x += mm[q] * vv[q].x; acc.y += mm[q] * vv[q].y;
            acc.z += mm[q] * vv[q].z; acc.w += mm[q] * vv[q].w;
        }
    }
    for (; j < e; ++j) {
        int s = colv[j];
        float m = sc ? sc[s] : 1.0f;
        float4 v = *reinterpret_cast<const float4*>(in + s * 32 + ln4);
        acc.x += m * v.x; acc.y += m * v.y; acc.z += m * v.z; acc.w += m * v.w;
    }
    *reinterpret_cast<float4*>(out + node * 32 + ln4) = acc;
}

// layer1: Tx1 = -dinv*g1; Tx2 = -2*dinv*g2 - x; h = relu(x*W1[0]+Tx1*W1[1]+Tx2*W1[2]+b1); hs = dinv*h
__global__ void k_layer1(const float* __restrict__ x, const float* __restrict__ g1,
                         const float* __restrict__ g2, const float* __restrict__ dinv,
                         const float* __restrict__ W1, const float* __restrict__ b1,
                         float* __restrict__ h, float* __restrict__ hs, int n) {
    int idx = blockIdx.x * BS + threadIdx.x;
    if (idx < n * 32) {
        int i = idx >> 5, f = idx & 31;
        float x0 = x[i], dv = dinv[i];
        float t1 = -dv * g1[i];
        float t2 = -2.0f * dv * g2[i] - x0;
        float v = x0 * W1[f] + t1 * W1[32 + f] + t2 * W1[64 + f] + b1[f];
        v = fmaxf(v, 0.0f);
        h[idx] = v;
        hs[idx] = dv * v;
    }
}

// layer2+fc: s1 = -dinv*gA; s2 = -2*dinv*gB - h; h2 = relu(h@W2[0]+s1@W2[1]+s2@W2[2]+b2); out = h2@Wfc+bfc
__global__ void k_layer2_fc(const float* __restrict__ h, const float* __restrict__ gA,
                            const float* __restrict__ gB, const float* __restrict__ dinv,
                            const float* __restrict__ W2, const float* __restrict__ b2,
                            const float* __restrict__ Wfc, const float* __restrict__ bfc,
                            float* __restrict__ out, int n) {
    __shared__ float W2s[3 * 32 * 32];
    int tid = threadIdx.x;
    for (int j = tid; j < 3 * 32 * 32; j += BS) W2s[j] = W2[j];
    __syncthreads();
    int f = tid & 31;
    int i = blockIdx.x * 8 + (tid >> 5);
    float acc = 0.0f;
    if (i < n) {
        float dv = dinv[i];
        acc = b2[f];
        const float* hr = h  + (size_t)i * 32;
        const float* ga = gA + (size_t)i * 32;
        const float* gb = gB + (size_t)i * 32;
        #pragma unroll
        for (int k = 0; k < 32; ++k) {
            float hk  = hr[k];
            float s1k = -dv * ga[k];
            float s2k = -2.0f * dv * gb[k] - hk;
            acc += hk * W2s[k * 32 + f] + s1k * W2s[1024 + k * 32 + f] + s2k * W2s[2048 + k * 32 + f];
        }
        acc = fmaxf(acc, 0.0f) * Wfc[f];
    }
    #pragma unroll
    for (int m = 16; m >= 1; m >>= 1) acc += __shfl_xor(acc, m, 32);
    if (i < n && f == 0) out[i] = acc + bfc[0];
}

extern "C" void kernel_launch(void* const* d_in, const int* in_sizes, int n_in,
                              void* d_out, int out_size, void* d_ws, size_t ws_size,
                              hipStream_t stream) {
    const float* x   = (const float*)d_in[0];
    const int*   ei  = (const int*)d_in[1];
    const float* W1  = (const float*)d_in[2];
    const float* b1  = (const float*)d_in[3];
    const float* W2  = (const float*)d_in[4];
    const float* b2  = (const float*)d_in[5];
    const float* Wfc = (const float*)d_in[6];
    const float* bfc = (const float*)d_in[7];
    float* out = (float*)d_out;

    const int n = in_sizes[0];
    const int E = in_sizes[1] / 2;
    const int* src = ei;
    const int* dst = ei + E;

    // workspace layout (4B words)
    int*   cnt8   = (int*)d_ws;                  // 8n (zeroed)
    int*   deg    = cnt8 + (size_t)NC * n;       // n  (zeroed)  [memset covers 9n]
    int*   cur8   = deg + n;                     // 8n
    int*   cnt    = cur8 + (size_t)NC * n;       // n
    int*   rowptr = cnt + n;                     // n+4
    int*   part   = rowptr + n + 4;              // 512
    float* dinv   = (float*)(part + 512);        // n
    float* u      = dinv + n;                    // n
    float* w      = u + n;                       // n
    float* g1     = w + n;                       // n
    float* v1     = g1 + n;                      // n
    float* g2     = v1 + n;                      // n
    int*   colv   = (int*)(g2 + n);              // E
    float* h      = (float*)(colv + E);          // 32n
    float* hs     = h + (size_t)32 * n;          // 32n; reused as gB
    float* gA     = hs + (size_t)32 * n;         // 32n
    float* gB     = hs;                          // alias
    int*   arena  = (int*)h;                     // E ints, overlaps h (dead until k_layer1)

    hipMemsetAsync(d_ws, 0, (size_t)(NC + 1) * n * sizeof(int), stream);

    const int EB  = (E + BS - 1) / BS;
    const int NB  = (n + BS - 1) / BS;
    const int L   = NC * n;
    const int NBA = (L + 2047) / 2048;           // <=512

    k_hist_cnt<<<NR * NC * 8, HB, 0, stream>>>(dst, cnt8, n, E);
    k_hist_deg<<<NR * 64, HB, 0, stream>>>(src, deg, n, E);
    k_dinv2<<<NB, BS, 0, stream>>>(deg, cnt8, x, dinv, u, w, cnt, n);
    // scan 1: flat cnt8 -> cur8 (arena offsets, copy-major so each copy region is disjoint)
    k_scanA_lin<<<NBA, BS, 0, stream>>>(cnt8, cur8, part, L);
    k_scanB<<<1, 512, 0, stream>>>(part, NBA);
    k_scanC_lin<<<(L + BS - 1) / BS, BS, 0, stream>>>(cur8, part, L);
    // scan 2: cnt -> rowptr (packed row starts)
    k_scan2A<<<NB, BS, 0, stream>>>(cnt, rowptr, part, n);
    k_scanB<<<1, 512, 0, stream>>>(part, NB);
    k_scan2C<<<NB + 1, BS, 0, stream>>>(rowptr, part, n, E);
    // arena fill + merge to packed colv
    k_build2<<<EB, BS, 0, stream>>>(src, dst, cur8, arena, n, E);
    k_merge<<<(n * 8 + BS - 1) / BS, BS, 0, stream>>>(arena, cur8, cnt8, rowptr, colv, n);

    // layer 1 (scalar)
    k_prop_s<<<NB, BS, 0, stream>>>(rowptr, colv, u, g1, v1, w, n);
    k_prop_s<<<NB, BS, 0, stream>>>(rowptr, colv, v1, g2, nullptr, nullptr, n);
    k_layer1<<<(n * 32 + BS - 1) / BS, BS, 0, stream>>>(x, g1, g2, dinv, W1, b1, h, hs, n);

    // layer 2 (32-dim)
    k_prop_v<<<(n * 8 + BS - 1) / BS, BS, 0, stream>>>(rowptr, colv, hs, gA, nullptr, n);
    k_prop_v<<<(n * 8 + BS - 1) / BS, BS, 0, stream>>>(rowptr, colv, gA, gB, w, n);
    k_layer2_fc<<<(n + 7) / 8, BS, 0, stream>>>(h, gA, gB, dinv, W2, b2, Wfc, bfc, out, n);
}